// Round 3
// baseline (567.945 us; speedup 1.0000x reference)
//
#include <hip/hip_runtime.h>
#include <math.h>

#define B_ 64
#define T_ 2048
#define DL 1024
#define DE 512
#define DA 128
#define NF 32
#define KW 31
#define PADW 15
#define TT 128

typedef short bf16x8 __attribute__((ext_vector_type(8)));
typedef float f32x4 __attribute__((ext_vector_type(4)));

// fragment-linear offset for a 128x32 (row, kin) tile:
// block index bi = row>>4 (0..7), lane = (kin>>3)*16 + (row&15), elem = kin&7
// off = (bi*64 + lane)*8 + elem ; hi at off, lo at off+4096
__device__ __forceinline__ int frag_off(int row, int kin) {
    return (((row >> 4) * 64 + (kin >> 3) * 16 + (row & 15)) << 3) + (kin & 7);
}

// truncation split: hi = trunc bf16, lo = trunc bf16 of remainder
__device__ __forceinline__ void split2_trunc(float x0, float x1, unsigned &h01, unsigned &l01) {
    unsigned u0 = __float_as_uint(x0), u1 = __float_as_uint(x1);
    h01 = __builtin_amdgcn_perm(u1, u0, 0x07060302u);
    float l0 = x0 - __uint_as_float(u0 & 0xFFFF0000u);
    float l1 = x1 - __uint_as_float(u1 & 0xFFFF0000u);
    l01 = __builtin_amdgcn_perm(__float_as_uint(l1), __float_as_uint(l0), 0x07060302u);
}

__device__ __forceinline__ void split1_trunc(float x, unsigned short &h, unsigned short &l) {
    unsigned u = __float_as_uint(x);
    h = (unsigned short)(u >> 16);
    float lf = x - __uint_as_float(u & 0xFFFF0000u);
    l = (unsigned short)(__float_as_uint(lf) >> 16);
}

__device__ __forceinline__ float fast_tanh(float x) {
    x = fminf(fmaxf(x, -15.f), 15.f);
    float e2 = __expf(2.f * x);
    return (e2 - 1.f) * __builtin_amdgcn_rcpf(e2 + 1.f);
}

// ---- prep: Wm [128][512] fp32 -> swizzled hi/lo bf16 fragment-linear, RNE ----
// per 32-k chunk c: 8192 ushorts (hi 4096 | lo 4096)
__global__ __launch_bounds__(256) void prep_kernel(const float* __restrict__ Wm,
                                                   unsigned short* __restrict__ Bsw) {
    int i = blockIdx.x * 256 + threadIdx.x;  // 65536
    int a = i >> 9, k = i & 511;
    float x = Wm[i];
    unsigned u = __float_as_uint(x);
    unsigned short h = (unsigned short)((u + 0x7FFFu + ((u >> 16) & 1u)) >> 16);
    float lf = x - __uint_as_float((unsigned)h << 16);
    unsigned ul = __float_as_uint(lf);
    unsigned short l = (unsigned short)((ul + 0x7FFFu + ((ul >> 16) & 1u)) >> 16);
    int c = k >> 5, kin = k & 31;
    size_t base = (size_t)c * 8192 + frag_off(a, kin);
    Bsw[base] = h;
    Bsw[base + 4096] = l;
}

// ---- q = query @ Wq.T + bq ----
__global__ __launch_bounds__(128) void q_kernel(const float* __restrict__ query,
                                                const float* __restrict__ Wq,
                                                const float* __restrict__ bq,
                                                float* __restrict__ qbuf) {
    int b = blockIdx.x;
    int a = threadIdx.x;
    __shared__ __align__(16) float qs[DL];
    for (int i = threadIdx.x; i < DL; i += 128) qs[i] = query[(size_t)b * DL + i];
    __syncthreads();
    const float* wrow = Wq + (size_t)a * DL;
    float acc = 0.f;
#pragma unroll 8
    for (int i = 0; i < DL; i += 4) {
        float4 w = *(const float4*)(wrow + i);
        float4 q4 = *(const float4*)(qs + i);
        acc += w.x * q4.x + w.y * q4.y + w.z * q4.z + w.w * q4.w;
    }
    qbuf[(size_t)b * DA + a] = acc + bq[a];
}

// ---- energies via split-bf16 MFMA, pipelined K-loop ----
__global__ __launch_bounds__(256, 3) void energy_kernel(
    const float* __restrict__ mem,            // [B,T,512]
    const float* __restrict__ attw,           // [B,2,T]
    const unsigned short* __restrict__ Bsw,   // swizzled Wm hi/lo
    const float* __restrict__ bm,
    const float* __restrict__ Wconv,          // [32,2,31]
    const float* __restrict__ Wloc,           // [128,32]
    const float* __restrict__ Wv,
    const float* __restrict__ bv,
    const float* __restrict__ qbuf,           // [B,128]
    float* __restrict__ e_out)                // [B,T]
{
    __shared__ __align__(16) unsigned short Abuf[8192];      // hi 4096 | lo 4096
    __shared__ __align__(16) unsigned short Bbuf[2][8192];   // dbuf, hi 4096 | lo 4096
    __shared__ float qb_s[DA], wv_s[DA];
    __shared__ float e_part[2][TT];

    const int tid = threadIdx.x;
    const int b = blockIdx.y;
    const int t0 = blockIdx.x * TT;
    const int lane = tid & 63;
    const int wave = tid >> 6;
    const int wm = wave & 1, wn = wave >> 1;
    const int m = lane & 15;

    // conv scratch aliases Bbuf[1] (16 KB >= 2368 floats)
    float* attw_s  = (float*)Bbuf[1];          // [2][160]
    float* wconv_s = (float*)Bbuf[1] + 320;    // [32][64]

    if (tid < DA) {
        qb_s[tid] = qbuf[(size_t)b * DA + tid] + bm[tid];
        wv_s[tid] = Wv[tid];
    }

    for (int i = tid; i < 2 * (TT + KW - 1); i += 256) {
        int c = i / 158, j = i % 158;
        int t = t0 - PADW + j;
        attw_s[c * 160 + j] = (t >= 0 && t < T_) ? attw[((size_t)b * 2 + c) * T_ + t] : 0.f;
    }
    for (int i = tid; i < NF * 2 * KW; i += 256) {
        int f = i / 62, r = i % 62;
        wconv_s[f * 64 + r] = Wconv[i];
    }
    // Wloc fragments -> Bbuf[0] (doesn't need attw scratch)
    for (int i = tid; i < DA * NF; i += 256) {
        int a = i >> 5, f = i & 31;
        unsigned short h, l;
        split1_trunc(Wloc[a * NF + f], h, l);
        int off = frag_off(a, f);
        Bbuf[0][off] = h;
        Bbuf[0][off + 4096] = l;
    }
    __syncthreads();

    // conv values -> Abuf fragments
    for (int i = tid; i < TT * NF; i += 256) {
        int t = i >> 5, f = i & 31;
        const float* w0 = wconv_s + f * 64;
        const float* a0 = attw_s + t;
        const float* a1 = attw_s + 160 + t;
        float s = 0.f;
#pragma unroll
        for (int k = 0; k < KW; ++k) s += w0[k] * a0[k] + w0[31 + k] * a1[k];
        unsigned short h, l;
        split1_trunc(s, h, l);
        int off = frag_off(t, f);
        Abuf[off] = h;
        Abuf[off + 4096] = l;
    }
    __syncthreads();

    f32x4 acc[4][4];
#pragma unroll
    for (int mi = 0; mi < 4; ++mi)
#pragma unroll
        for (int ni = 0; ni < 4; ++ni) {
            f32x4 z = {0.f, 0.f, 0.f, 0.f};
            acc[mi][ni] = z;
        }

    auto mfma_step = [&](const unsigned short* Bb) {
        bf16x8 ah[4], al[4];
#pragma unroll
        for (int mi = 0; mi < 4; ++mi) {
            const unsigned short* p = Abuf + (((wm * 4 + mi) * 64 + lane) << 3);
            ah[mi] = *(const bf16x8*)p;
            al[mi] = *(const bf16x8*)(p + 4096);
        }
#pragma unroll
        for (int ni = 0; ni < 4; ++ni) {
            const unsigned short* p = Bb + (((wn * 4 + ni) * 64 + lane) << 3);
            bf16x8 bh = *(const bf16x8*)p;
            bf16x8 bl = *(const bf16x8*)(p + 4096);
#pragma unroll
            for (int mi = 0; mi < 4; ++mi) {
                acc[mi][ni] = __builtin_amdgcn_mfma_f32_16x16x32_bf16(ah[mi], bh, acc[mi][ni], 0, 0, 0);
                acc[mi][ni] = __builtin_amdgcn_mfma_f32_16x16x32_bf16(ah[mi], bl, acc[mi][ni], 0, 0, 0);
                acc[mi][ni] = __builtin_amdgcn_mfma_f32_16x16x32_bf16(al[mi], bh, acc[mi][ni], 0, 0, 0);
            }
        }
    };

    // async B staging: 16 KB chunk via global_load_lds width-16
    auto issue_B = [&](int c, unsigned short* dst) {
        const unsigned char* g = (const unsigned char*)Bsw + (size_t)c * 16384 + wave * 4096 + lane * 16;
        unsigned char* l = (unsigned char*)dst + wave * 4096;
#pragma unroll
        for (int it = 0; it < 4; ++it)
            __builtin_amdgcn_global_load_lds(
                (const __attribute__((address_space(1))) unsigned*)(g + it * 1024),
                (__attribute__((address_space(3))) unsigned*)(l + it * 1024), 16, 0, 0);
    };

    const size_t mem_base = ((size_t)b * T_ + t0) * DE;
    const int tA = tid >> 3;             // base row (0..31), +32 per r
    const int c4 = (tid & 7) * 4;        // k-offset within chunk

    float4 ap[4];
    auto load_A = [&](int c) {
        const float* p = mem + mem_base + (size_t)tA * DE + c * 32 + c4;
#pragma unroll
        for (int r = 0; r < 4; ++r) ap[r] = *(const float4*)(p + (size_t)r * 32 * DE);
    };
    auto store_A = [&]() {
        int off0 = frag_off(tA, c4);
#pragma unroll
        for (int r = 0; r < 4; ++r) {
            unsigned h01, l01, h23, l23;
            split2_trunc(ap[r].x, ap[r].y, h01, l01);
            split2_trunc(ap[r].z, ap[r].w, h23, l23);
            int off = off0 + r * 1024;   // +32 rows = +2 blocks of 512
            uint2 hv = {h01, h23}, lv = {l01, l23};
            *(uint2*)(Abuf + off) = hv;
            *(uint2*)(Abuf + off + 4096) = lv;
        }
    };

    mfma_step(Bbuf[0]);   // conv/location chunk
    load_A(0);
    __syncthreads();      // all waves done with conv Abuf/Bbuf[0]
    issue_B(0, Bbuf[0]);
    store_A();
    __syncthreads();      // drains vmcnt: B[0] in LDS, A[0] visible

    for (int c = 0; c < 16; ++c) {
        if (c < 15) {
            load_A(c + 1);                    // global loads in flight during MFMA
            issue_B(c + 1, Bbuf[(c + 1) & 1]);
        }
        mfma_step(Bbuf[c & 1]);
        __syncthreads();                      // done reading Abuf; drains prefetches
        if (c < 15) store_A();
        __syncthreads();
    }

    // epilogue: e[t] = bv + sum_a wv[a]*tanh(acc + qb[a])
    float wvr[4], qbr[4];
#pragma unroll
    for (int ni = 0; ni < 4; ++ni) {
        int a = wn * 64 + ni * 16 + m;
        wvr[ni] = wv_s[a];
        qbr[ni] = qb_s[a];
    }
    float bvv = bv[0];
#pragma unroll
    for (int mi = 0; mi < 4; ++mi) {
#pragma unroll
        for (int reg = 0; reg < 4; ++reg) {
            float s = 0.f;
#pragma unroll
            for (int ni = 0; ni < 4; ++ni)
                s += wvr[ni] * fast_tanh(acc[mi][ni][reg] + qbr[ni]);
            s += __shfl_xor(s, 1, 64);
            s += __shfl_xor(s, 2, 64);
            s += __shfl_xor(s, 4, 64);
            s += __shfl_xor(s, 8, 64);
            if (m == 0)
                e_part[wn][wm * 64 + mi * 16 + (lane >> 4) * 4 + reg] = s;
        }
    }
    __syncthreads();
    if (tid < TT)
        e_out[(size_t)b * T_ + t0 + tid] = e_part[0][tid] + e_part[1][tid] + bvv;
}

// ---- softmax over T per b ----
__global__ __launch_bounds__(256) void softmax_kernel(const float* __restrict__ e,
                                                      float* __restrict__ wout) {
    int b = blockIdx.x;
    int tid = threadIdx.x;
    __shared__ float red[4];
    float v[8];
    float m = -1e30f;
#pragma unroll
    for (int r = 0; r < 8; ++r) {
        v[r] = e[(size_t)b * T_ + r * 256 + tid];
        m = fmaxf(m, v[r]);
    }
#pragma unroll
    for (int off = 1; off < 64; off <<= 1) m = fmaxf(m, __shfl_xor(m, off, 64));
    if ((tid & 63) == 0) red[tid >> 6] = m;
    __syncthreads();
    m = fmaxf(fmaxf(red[0], red[1]), fmaxf(red[2], red[3]));
    __syncthreads();
    float s = 0.f;
#pragma unroll
    for (int r = 0; r < 8; ++r) {
        v[r] = expf(v[r] - m);
        s += v[r];
    }
#pragma unroll
    for (int off = 1; off < 64; off <<= 1) s += __shfl_xor(s, off, 64);
    if ((tid & 63) == 0) red[tid >> 6] = s;
    __syncthreads();
    s = red[0] + red[1] + red[2] + red[3];
    float inv = 1.0f / s;
#pragma unroll
    for (int r = 0; r < 8; ++r) wout[(size_t)b * T_ + r * 256 + tid] = v[r] * inv;
}

// ---- context partials (float4) ----
__global__ __launch_bounds__(256) void ctx_partial_kernel(const float* __restrict__ mem,
                                                          const float* __restrict__ w,
                                                          float* __restrict__ partial) {
    int b = blockIdx.y, tc = blockIdx.x;
    int tid = threadIdx.x;
    __shared__ float ws_s[128];
    __shared__ float red[512];
    if (tid < 128) ws_s[tid] = w[(size_t)b * T_ + tc * 128 + tid];
    __syncthreads();
    int d = (tid & 127) * 4;
    int th = tid >> 7;
    const float* mp = mem + ((size_t)b * T_ + tc * 128 + th * 64) * DE + d;
    float a0 = 0.f, a1 = 0.f, a2 = 0.f, a3 = 0.f;
#pragma unroll 8
    for (int t = 0; t < 64; ++t) {
        float4 v = *(const float4*)(mp + (size_t)t * DE);
        float wv = ws_s[th * 64 + t];
        a0 += wv * v.x; a1 += wv * v.y; a2 += wv * v.z; a3 += wv * v.w;
    }
    if (th == 1) {
        float* r = red + (tid & 127) * 4;
        r[0] = a0; r[1] = a1; r[2] = a2; r[3] = a3;
    }
    __syncthreads();
    if (th == 0) {
        const float* r = red + tid * 4;
        float* pp = partial + ((size_t)b * 16 + tc) * DE + d;
        pp[0] = a0 + r[0]; pp[1] = a1 + r[1]; pp[2] = a2 + r[2]; pp[3] = a3 + r[3];
    }
}

// ---- reduce partials -> context ----
__global__ __launch_bounds__(512) void ctx_reduce_kernel(const float* __restrict__ partial,
                                                         float* __restrict__ ctx) {
    int b = blockIdx.x;
    int d = threadIdx.x;
    float s = 0.f;
#pragma unroll
    for (int j = 0; j < 16; ++j) s += partial[((size_t)b * 16 + j) * DE + d];
    ctx[(size_t)b * DE + d] = s;
}

extern "C" void kernel_launch(void* const* d_in, const int* in_sizes, int n_in,
                              void* d_out, int out_size, void* d_ws, size_t ws_size,
                              hipStream_t stream) {
    const float* query  = (const float*)d_in[0];
    const float* memory = (const float*)d_in[1];
    const float* attw   = (const float*)d_in[2];
    const float* Wq     = (const float*)d_in[3];
    const float* bq     = (const float*)d_in[4];
    const float* Wm     = (const float*)d_in[5];
    const float* bm     = (const float*)d_in[6];
    const float* Wconv  = (const float*)d_in[7];
    const float* Wloc   = (const float*)d_in[8];
    const float* Wv     = (const float*)d_in[9];
    const float* bv     = (const float*)d_in[10];

    float* out = (float*)d_out;
    float* ctx_out = out;          // [64,512]
    float* w_out = out + B_ * DE;  // [64,2048]

    float* ws = (float*)d_ws;
    float* qbuf = ws;                         // 8192 f
    float* ebuf = qbuf + B_ * DA;             // 131072 f
    float* partial = ebuf + (size_t)B_ * T_;  // 524288 f
    unsigned short* Bsw = (unsigned short*)(partial + (size_t)B_ * 16 * DE);  // 131072 ush

    prep_kernel<<<dim3(DA * DE / 256), dim3(256), 0, stream>>>(Wm, Bsw);
    q_kernel<<<dim3(B_), dim3(128), 0, stream>>>(query, Wq, bq, qbuf);
    energy_kernel<<<dim3(T_ / TT, B_), dim3(256), 0, stream>>>(
        memory, attw, Bsw, bm, Wconv, Wloc, Wv, bv, qbuf, ebuf);
    softmax_kernel<<<dim3(B_), dim3(256), 0, stream>>>(ebuf, w_out);
    ctx_partial_kernel<<<dim3(16, B_), dim3(256), 0, stream>>>(memory, w_out, partial);
    ctx_reduce_kernel<<<dim3(B_), dim3(512), 0, stream>>>(partial, ctx_out);
}